// Round 14
// baseline (246.001 us; speedup 1.0000x reference)
//
#include <hip/hip_runtime.h>
#include <hip/hip_bf16.h>
#include <cstddef>

// Problem constants (match reference)
constexpr int NN = 20000;   // nodes
constexpr int NE = 320000;  // edges
constexpr int NHEAD = 4;
constexpr int ND = 128;     // per-head dim
constexpr int HD = 512;     // H*D
constexpr int MPAD = 20096; // 157*128 padded rows for GEMM tiles
constexpr int SLOTS = 64;   // padded-CSR slots per node (Poisson(16): P(>64)~1e-20)
constexpr float NEG_SLOPE = 0.2f;

using short8 = __attribute__((ext_vector_type(8))) short;
using f32x4 = __attribute__((ext_vector_type(4))) float;
using f32x2 = __attribute__((ext_vector_type(2))) float;

// async global->LDS, 16B per lane, LDS dest = wave-uniform base + lane*16
__device__ inline void gload16(const void* g, void* l) {
  __builtin_amdgcn_global_load_lds(
      (const __attribute__((address_space(1))) void*)g,
      (__attribute__((address_space(3))) void*)l, 16, 0, 0);
}

// fp8 e4m3 (OCP on gfx950) encode one float -> byte
__device__ inline unsigned char f32_to_fp8(float v) {
  int pk = __builtin_amdgcn_cvt_pk_fp8_f32(v, v, 0, false);
  return (unsigned char)(pk & 0xff);
}

// ---------------- fused prep --------------------------------------------------
// Segments: [cnt zero][feats->bf16 pad][W1^T bf16][vcomb][partials zero]
// vcomb[v][k], v = 0..11: v<4 -> vl[h=v], v<8 -> vr[h=v-4], else vq[h=v-8]:
//   vl[h,k] = sum_d W2[k, h*128+d] * al2[h,d]   (el2 = h1 . vl — logits stay
//   >= bf16 precision; fp8 logits failed in R10)
constexpr int S0 = NN;                      // cnt zero
constexpr int S1 = S0 + MPAD * 128;         // featsb
constexpr int S2 = S1 + 512 * 128;          // W1t
constexpr int S3 = S2 + 12 * 512;           // vcomb
constexpr int S4 = S3 + 256;                // partials zero
__global__ __launch_bounds__(256) void prep_kernel(
    const float* __restrict__ feats, const float* __restrict__ W1,
    const float* __restrict__ W2, const float* __restrict__ al2,
    const float* __restrict__ ar2, const float* __restrict__ Wr,
    __hip_bfloat16* __restrict__ featsb, __hip_bfloat16* __restrict__ W1t,
    float* __restrict__ vcomb, float* __restrict__ partials,
    int* __restrict__ cnt) {
  int t = blockIdx.x * 256 + threadIdx.x;
  if (t < S0) {
    cnt[t] = 0;
  } else if (t < S1) {
    int u = t - S0;
    featsb[u] = __float2bfloat16(u < NN * 128 ? feats[u] : 0.f);
  } else if (t < S2) {
    int u = t - S1;                       // W1t[m][k], m=u>>7, k=u&127
    W1t[u] = __float2bfloat16(W1[(size_t)(u & 127) * 512 + (u >> 7)]);
  } else if (t < S3) {
    int u = t - S2;                       // vcomb[v][k]
    int v = u >> 9, k = u & 511;
    int h = (v < 4) ? v : (v < 8) ? v - 4 : v - 8;
    const float* vec = (v < 4) ? (al2 + h * 128)
                     : (v < 8) ? (ar2 + h * 128) : Wr;
    const float* wrow = W2 + (size_t)k * 512 + h * 128;
    float s = 0.f;
    for (int d = 0; d < 128; ++d) s += wrow[d] * vec[d];
    vcomb[u] = s;
  } else if (t < S4) {
    partials[t - S3] = 0.f;
  }
}

// ---------------- layer-1 bf16 MFMA GEMM + el/er epilogue, HEAD-SPLIT fp8 z --
// Prologue: grid-stride padded-CSR fill (cnt zeroed by prep).
// zh[head][Mpad][128] (fp8) = A[Mpad][128] @ W1t[512][128]^T.  128x128 tile,
// 256 threads = 4 waves, each 64x64 via 4x4 mfma_16x16x32.  blockIdx.y = head.
// Head-split z: each head region is 2.57 MB (< 4 MB XCD L2) so the aggregate's
// XCD-pinned gathers become L2-resident.  el/er from fp32 accumulators.
__global__ __launch_bounds__(256) void gemm1_kernel(
    const __hip_bfloat16* __restrict__ A,   // [Mpad][128] bf16
    const __hip_bfloat16* __restrict__ Bt,  // [512][128] bf16 (W1^T)
    unsigned char* __restrict__ zh,         // [4][Mpad][128] fp8
    const float* __restrict__ al, const float* __restrict__ ar,
    float* __restrict__ el, float* __restrict__ er,
    const int* __restrict__ src, const int* __restrict__ dst,
    int* __restrict__ cnt, int* __restrict__ src_perm) {
  constexpr int K = 128;
  __shared__ short As[128 * 32];
  __shared__ short Bs[128 * 32];
  __shared__ float elbuf[4][128];
  __shared__ float erbuf[4][128];
  int t = threadIdx.x;

  // ---- CSR fill prologue (completes before aggregate by stream order) ----
  {
    int nth = gridDim.x * gridDim.y * 256;
    int gid = (blockIdx.y * gridDim.x + blockIdx.x) * 256 + t;
    for (int e = gid; e < NE; e += nth) {
      int d = dst[e];
      int p = atomicAdd(&cnt[d], 1);
      if (p < SLOTS) src_perm[d * SLOTS + p] = src[e];
    }
  }

  int lane = t & 63;
  int wave = t >> 6;
  int rowBase = blockIdx.x * 128;
  int head = blockIdx.y;
  int colBase = head * 128;
  int woffr = (wave & 1) * 64;
  int woffc = (wave >> 1) * 64;
  int mrow = lane & 15, quad = lane >> 4;

  f32x4 acc[4][4];
#pragma unroll
  for (int i = 0; i < 4; ++i)
#pragma unroll
    for (int j = 0; j < 4; ++j) acc[i][j] = (f32x4){0.f, 0.f, 0.f, 0.f};

  for (int k0 = 0; k0 < K; k0 += 32) {
#pragma unroll
    for (int p = 0; p < 2; ++p) {
      int f = p * 256 + wave * 64 + lane;
      int r = f >> 2, kc = f & 3;
      gload16(A + (size_t)(rowBase + r) * K + k0 + kc * 8,
              As + p * 2048 + wave * 512);
      gload16(Bt + (size_t)(colBase + r) * K + k0 + kc * 8,
              Bs + p * 2048 + wave * 512);
    }
    __syncthreads();
    short8 af[4], bfr[4];
#pragma unroll
    for (int i = 0; i < 4; ++i)
      af[i] = *(const short8*)&As[(woffr + i * 16 + mrow) * 32 + quad * 8];
#pragma unroll
    for (int j = 0; j < 4; ++j)
      bfr[j] = *(const short8*)&Bs[(woffc + j * 16 + mrow) * 32 + quad * 8];
#pragma unroll
    for (int i = 0; i < 4; ++i)
#pragma unroll
      for (int j = 0; j < 4; ++j)
        acc[i][j] = __builtin_amdgcn_mfma_f32_16x16x32_bf16(af[i], bfr[j], acc[i][j], 0, 0, 0);
    __syncthreads();
  }

  // z store (fp8, head-split). C/D layout: col = lane&15, row = quad*4 + reg
  unsigned char* zreg = zh + (size_t)head * MPAD * 128;
#pragma unroll
  for (int i = 0; i < 4; ++i) {
#pragma unroll
    for (int j = 0; j < 4; ++j) {
      int colh = woffc + j * 16 + mrow;            // col within head [0,128)
#pragma unroll
      for (int r = 0; r < 4; ++r) {
        int row = rowBase + woffr + i * 16 + quad * 4 + r;
        zreg[(size_t)row * 128 + colh] = f32_to_fp8(acc[i][j][r]);
      }
    }
  }

  // fused el/er epilogue from fp32 accumulators
  float al_v[4], ar_v[4];
#pragma unroll
  for (int j = 0; j < 4; ++j) {
    int coll = woffc + j * 16 + mrow;
    al_v[j] = al[head * 128 + coll];
    ar_v[j] = ar[head * 128 + coll];
  }
#pragma unroll
  for (int i = 0; i < 4; ++i) {
#pragma unroll
    for (int r = 0; r < 4; ++r) {
      float pl = 0.f, pr = 0.f;
#pragma unroll
      for (int j = 0; j < 4; ++j) {
        float v = acc[i][j][r];
        pl += v * al_v[j];
        pr += v * ar_v[j];
      }
#pragma unroll
      for (int off = 1; off < 16; off <<= 1) {
        pl += __shfl_xor(pl, off);
        pr += __shfl_xor(pr, off);
      }
      if (mrow == 0) {
        int row128 = woffr + i * 16 + quad * 4 + r;
        elbuf[wave][row128] = pl;
        erbuf[wave][row128] = pr;
      }
    }
  }
  __syncthreads();
  if (t < 128) {
    int row = t;
    int w0 = (row < 64) ? 0 : 1;
    float ev = elbuf[w0][row] + elbuf[w0 + 2][row];
    float rv = erbuf[w0][row] + erbuf[w0 + 2][row];
    int gr = rowBase + row;
    if (gr < NN) {
      el[gr * 4 + head] = ev;
      er[gr * 4 + head] = rv;
    }
  }
}

// ---------------- layer-1 attn + aggregation: one wave per (node, head) -----
// XCD-pinned: xcd = bid&7, head = xcd>>1 -> each head's 2.57 MB z region is
// served by one XCD pair's L2 (under round-robin block->XCD dispatch).
// Phase 1 (lane = slot): alpha for THIS head via exp(leaky_relu(el1[src]+
// er1[n])) (softmax shift-invariance -> segment_max skipped), butterfly denom,
// alpha -> LDS (same-wave).
// Phase 2: 4 edges in flight (16-lane dim groups, 8 dims each -> one 128 B
// contiguous group read per edge), x2 unroll = 8 outstanding; shfl_xor 16/32
// combines groups.  h1 slice written bf16 (proven precision for logits, R9).
__global__ __launch_bounds__(256) void aggregate_kernel(
    const unsigned char* __restrict__ zh,   // [4][MPAD][128] fp8
    const int* __restrict__ cnt,
    const int* __restrict__ src_perm,
    const float* __restrict__ el,           // layer-1 logits [NN][4]
    const float* __restrict__ er,
    const float* __restrict__ b1,           // [512]
    __hip_bfloat16* __restrict__ h1b) {     // [NN][512] bf16
  __shared__ float alds[4][SLOTS];
  int bid = blockIdx.x;
  int xcd = bid & 7;
  int head = xcd >> 1;                      // heads pinned to XCD pairs
  int grp = (bid >> 3) * 2 + (xcd & 1);     // 0..4999
  int wv = __builtin_amdgcn_readfirstlane((int)(threadIdx.x >> 6));
  int n = grp * 4 + wv;
  int lane = threadIdx.x & 63;
  int c = min(cnt[n], SLOTS);
  int base = n * SLOTS;

  // ---- phase 1: per-head alpha (lane = slot) ----
  {
    float ern = er[n * 4 + head];
    float a = 0.f;
    if (lane < c) {
      int s = src_perm[base + lane];
      float x = el[s * 4 + head] + ern;
      x = (x > 0.f) ? x : NEG_SLOPE * x;
      a = __expf(x);
    }
    float ssum = a;
#pragma unroll
    for (int off = 1; off < 64; off <<= 1) ssum += __shfl_xor(ssum, off);
    alds[wv][lane] = a / fmaxf(ssum, 1e-9f);   // same-wave producer/consumer
  }

  // ---- phase 2: group g = lane>>4 handles edges i+g (4 in flight, x2) ----
  int g = lane >> 4, li = lane & 15;
  const unsigned char* zbase = zh + (size_t)head * MPAD * 128 + li * 8;
  float acc[8] = {};

#define EDGE_BODY(E)                                                           \
  if ((E) < c) {                                                               \
    int s = src_perm[base + (E)];                                              \
    float aa = alds[wv][(E)];                                                  \
    uint2 w = *reinterpret_cast<const uint2*>(zbase + (size_t)s * 128);        \
    f32x2 f0 = __builtin_amdgcn_cvt_pk_f32_fp8(w.x, false);                    \
    f32x2 f1 = __builtin_amdgcn_cvt_pk_f32_fp8(w.x, true);                     \
    f32x2 f2 = __builtin_amdgcn_cvt_pk_f32_fp8(w.y, false);                    \
    f32x2 f3 = __builtin_amdgcn_cvt_pk_f32_fp8(w.y, true);                     \
    acc[0] += aa * f0.x; acc[1] += aa * f0.y;                                  \
    acc[2] += aa * f1.x; acc[3] += aa * f1.y;                                  \
    acc[4] += aa * f2.x; acc[5] += aa * f2.y;                                  \
    acc[6] += aa * f3.x; acc[7] += aa * f3.y;                                  \
  }

  for (int i = 0; i < c; i += 8) {
    EDGE_BODY(i + g)
    EDGE_BODY(i + 4 + g)
  }
#undef EDGE_BODY

  // combine the 4 dim-groups (lanes with equal li hold the same dims)
#pragma unroll
  for (int j = 0; j < 8; ++j) {
    acc[j] += __shfl_xor(acc[j], 16);
    acc[j] += __shfl_xor(acc[j], 32);
  }

  float v[8];
#pragma unroll
  for (int j = 0; j < 8; ++j) {
    float x = acc[j] + b1[head * 128 + li * 8 + j];
    v[j] = (x > 0.f) ? x : expm1f(x);
  }
  if (lane < 16) {
    __hip_bfloat162 o[4];
#pragma unroll
    for (int j = 0; j < 4; ++j)
      o[j] = __float22bfloat162_rn(make_float2(v[2 * j], v[2 * j + 1]));
    *reinterpret_cast<uint4*>(h1b + (size_t)n * HD + head * 128 + li * 8) =
        *reinterpret_cast<const uint4*>(o);
  }
}

// ---------------- layer-2 projections: el2/er2/q = h1 . vcomb ---------------
// One wave per node, dense streamed read of h1 (20 MB), 12 dot products with
// the W2-folded vcomb vectors (GEMM2 eliminated algebraically).
__global__ __launch_bounds__(256) void proj_kernel(
    const __hip_bfloat16* __restrict__ h1b, // [NN][512] bf16
    const float* __restrict__ vcomb,        // [12][512]
    float* __restrict__ el2, float* __restrict__ er2,
    float* __restrict__ q2) {               // [NN][4] each
  int wv = __builtin_amdgcn_readfirstlane((int)(threadIdx.x >> 6));
  int n = blockIdx.x * 4 + wv;
  int lane = threadIdx.x & 63;
  // lane's 8 dims
  const __hip_bfloat162* hp =
      reinterpret_cast<const __hip_bfloat162*>(h1b + (size_t)n * HD + lane * 8);
  float2 h0 = __bfloat1622float2(hp[0]);
  float2 h1 = __bfloat1622float2(hp[1]);
  float2 h2 = __bfloat1622float2(hp[2]);
  float2 h3 = __bfloat1622float2(hp[3]);
  float r[12];
#pragma unroll
  for (int vv = 0; vv < 12; ++vv) {
    const float* vb = vcomb + vv * 512 + lane * 8;
    float4 cA = *reinterpret_cast<const float4*>(vb);
    float4 cB = *reinterpret_cast<const float4*>(vb + 4);
    float p = h0.x * cA.x + h0.y * cA.y + h1.x * cA.z + h1.y * cA.w +
              h2.x * cB.x + h2.y * cB.y + h3.x * cB.z + h3.y * cB.w;
#pragma unroll
    for (int off = 1; off < 64; off <<= 1) p += __shfl_xor(p, off);
    r[vv] = p;
  }
  if (lane == 0) {
    *reinterpret_cast<float4*>(&el2[n * 4]) = make_float4(r[0], r[1], r[2], r[3]);
    *reinterpret_cast<float4*>(&er2[n * 4]) = make_float4(r[4], r[5], r[6], r[7]);
    *reinterpret_cast<float4*>(&q2[n * 4]) = make_float4(r[8], r[9], r[10], r[11]);
  }
}

// ---------------- layer-2 attention + readout dot ---------------------------
// One wave per dst node (lane = slot): alpha butterfly, dot with q[src] (16 B
// L2-resident gather), block partial -> 256-slot atomics.  NO device fence /
// done counter (cost ~90 µs in R11).
__global__ __launch_bounds__(256) void attn_q_kernel(
    const int* __restrict__ src_perm,
    const int* __restrict__ cnt,
    const float* __restrict__ el,
    const float* __restrict__ er,
    const float* __restrict__ q,            // [NN][4]
    float* __restrict__ partials) {         // [256]
  __shared__ float blk[4];
  int wv = __builtin_amdgcn_readfirstlane((int)(threadIdx.x >> 6));
  int n = blockIdx.x * 4 + wv;
  int lane = threadIdx.x & 63;
  int c = min(cnt[n], SLOTS);
  float4 er4 = *reinterpret_cast<const float4*>(&er[n * 4]);
  float a0 = 0.f, a1 = 0.f, a2 = 0.f, a3 = 0.f;
  int s = 0;
  if (lane < c) {
    s = src_perm[n * SLOTS + lane];
    float4 e4 = *reinterpret_cast<const float4*>(&el[s * 4]);
    float x0 = e4.x + er4.x, x1 = e4.y + er4.y;
    float x2 = e4.z + er4.z, x3 = e4.w + er4.w;
    x0 = (x0 > 0.f) ? x0 : NEG_SLOPE * x0;
    x1 = (x1 > 0.f) ? x1 : NEG_SLOPE * x1;
    x2 = (x2 > 0.f) ? x2 : NEG_SLOPE * x2;
    x3 = (x3 > 0.f) ? x3 : NEG_SLOPE * x3;
    a0 = __expf(x0); a1 = __expf(x1); a2 = __expf(x2); a3 = __expf(x3);
  }
  float s0 = a0, s1 = a1, s2 = a2, s3 = a3;
#pragma unroll
  for (int off = 1; off < 64; off <<= 1) {
    s0 += __shfl_xor(s0, off);
    s1 += __shfl_xor(s1, off);
    s2 += __shfl_xor(s2, off);
    s3 += __shfl_xor(s3, off);
  }
  float p = 0.f;
  if (lane < c) {
    float4 q4 = *reinterpret_cast<const float4*>(&q[s * 4]);
    p = (a0 / fmaxf(s0, 1e-9f)) * q4.x + (a1 / fmaxf(s1, 1e-9f)) * q4.y +
        (a2 / fmaxf(s2, 1e-9f)) * q4.z + (a3 / fmaxf(s3, 1e-9f)) * q4.w;
  }
#pragma unroll
  for (int off = 32; off > 0; off >>= 1) p += __shfl_down(p, off);
  if (lane == 0) blk[wv] = p;
  __syncthreads();
  if (threadIdx.x == 0) {
    atomicAdd(&partials[blockIdx.x & 255], blk[0] + blk[1] + blk[2] + blk[3]);
  }
}

// ---------------- final: out = 0.25*(sum partials + NN*b2.Wr_rep) + NN*br ----
__global__ __launch_bounds__(512) void final_kernel(
    const float* __restrict__ partials, const float* __restrict__ b2,
    const float* __restrict__ Wr, const float* __restrict__ br,
    float* __restrict__ out) {
  __shared__ float tmp[512];
  int t = threadIdx.x;
  float sum = (t < 256) ? partials[t] : 0.f;
  sum += (float)NN * b2[t] * Wr[t & 127];
  tmp[t] = sum;
  __syncthreads();
  for (int off = 256; off > 0; off >>= 1) {
    if (t < off) tmp[t] += tmp[t + off];
    __syncthreads();
  }
  if (t == 0) out[0] = 0.25f * tmp[0] + (float)NN * br[0];
}

// ---------------- launch ----------------
extern "C" void kernel_launch(void* const* d_in, const int* in_sizes, int n_in,
                              void* d_out, int out_size, void* d_ws, size_t ws_size,
                              hipStream_t stream) {
  const float* feats = (const float*)d_in[0];
  const int* src = (const int*)d_in[1];
  const int* dst = (const int*)d_in[2];
  const float* W1 = (const float*)d_in[3];
  const float* al1 = (const float*)d_in[4];
  const float* ar1 = (const float*)d_in[5];
  const float* b1 = (const float*)d_in[6];
  const float* W2 = (const float*)d_in[7];
  const float* al2 = (const float*)d_in[8];
  const float* ar2 = (const float*)d_in[9];
  const float* b2 = (const float*)d_in[10];
  const float* Wr = (const float*)d_in[11];
  const float* br = (const float*)d_in[12];
  float* out = (float*)d_out;

  // workspace layout (~42 MB); all section sizes multiples of 16 B
  __hip_bfloat16* featsb = (__hip_bfloat16*)d_ws;               // MPAD*128 bf16
  unsigned char* zh = (unsigned char*)(featsb + (size_t)MPAD * 128); // 4*MPAD*128 fp8
  __hip_bfloat16* h1b = (__hip_bfloat16*)(zh + (size_t)MPAD * HD);   // MPAD*512 bf16
  __hip_bfloat16* W1t = h1b + (size_t)MPAD * HD;                // 512*128 bf16
  float* vcomb = (float*)(W1t + 512 * 128);                     // 12*512 f32
  float* el1 = vcomb + 12 * 512;                                // NN*4
  float* er1 = el1 + (size_t)NN * NHEAD;                        // NN*4
  float* el2 = er1 + (size_t)NN * NHEAD;                        // NN*4
  float* er2 = el2 + (size_t)NN * NHEAD;                        // NN*4
  float* q2 = er2 + (size_t)NN * NHEAD;                         // NN*4
  float* partials = q2 + (size_t)NN * NHEAD;                    // 256
  int* cnt = (int*)(partials + 256 + 4);                        // NN
  int* src_perm = cnt + NN;                                     // NN*SLOTS

  // prep: cnt zero + feats->bf16 + W1^T + vcomb + partials zero (1 dispatch)
  prep_kernel<<<(S4 + 255) / 256, 256, 0, stream>>>(
      feats, W1, W2, al2, ar2, Wr, featsb, W1t, vcomb, partials, cnt);

  dim3 gemm_grid(MPAD / 128, NHEAD);

  // gemm1: CSR-fill prologue + GEMM (head-split fp8 z + el/er epilogue)
  gemm1_kernel<<<gemm_grid, 256, 0, stream>>>(featsb, W1t, zh, al1, ar1,
                                              el1, er1, src, dst, cnt, src_perm);

  // layer-1 attn+aggregate, one wave per (node,head), XCD-pinned heads
  aggregate_kernel<<<NN, 256, 0, stream>>>(zh, cnt, src_perm, el1, er1, b1, h1b);

  // layer-2 projections from bf16 h1 (GEMM2 folded into 12 dots)
  proj_kernel<<<NN / 4, 256, 0, stream>>>(h1b, vcomb, el2, er2, q2);

  // layer-2 attention + readout dot, then tiny final reduce
  attn_q_kernel<<<NN / 4, 256, 0, stream>>>(src_perm, cnt, el2, er2, q2, partials);
  final_kernel<<<1, 512, 0, stream>>>(partials, b2, Wr, br, out);
}

// Round 15
// 174.734 us; speedup vs baseline: 1.4079x; 1.4079x over previous
//
#include <hip/hip_runtime.h>
#include <hip/hip_bf16.h>
#include <cstddef>

// Problem constants (match reference)
constexpr int NN = 20000;   // nodes
constexpr int NE = 320000;  // edges
constexpr int NHEAD = 4;
constexpr int ND = 128;     // per-head dim
constexpr int HD = 512;     // H*D
constexpr int MPAD = 20096; // 157*128 padded rows for GEMM tiles
constexpr int SLOTS = 64;   // padded-CSR slots per node (Poisson(16): P(>64)~1e-20)
constexpr float NEG_SLOPE = 0.2f;

using short8 = __attribute__((ext_vector_type(8))) short;
using f32x4 = __attribute__((ext_vector_type(4))) float;
using f32x2 = __attribute__((ext_vector_type(2))) float;

// async global->LDS, 16B per lane, LDS dest = wave-uniform base + lane*16
__device__ inline void gload16(const void* g, void* l) {
  __builtin_amdgcn_global_load_lds(
      (const __attribute__((address_space(1))) void*)g,
      (__attribute__((address_space(3))) void*)l, 16, 0, 0);
}

// fp8 e4m3 (OCP on gfx950) encode one float -> byte
__device__ inline unsigned char f32_to_fp8(float v) {
  int pk = __builtin_amdgcn_cvt_pk_fp8_f32(v, v, 0, false);
  return (unsigned char)(pk & 0xff);
}

// ---------------- fused prep --------------------------------------------------
// Segments: [cnt zero][feats->bf16 pad][W1^T bf16][vcomb][partials zero]
// vcomb[v][k], v = 0..11: v<4 -> vl[h=v], v<8 -> vr[h=v-4], else vq[h=v-8]:
//   vl[h,k] = sum_d W2[k, h*128+d] * al2[h,d]   (el2 = h1 . vl, fp32 — the
//   attention logits keep full precision; fp8 logits failed in R10)
constexpr int S0 = NN;                      // cnt zero
constexpr int S1 = S0 + MPAD * 128;         // featsb
constexpr int S2 = S1 + 512 * 128;          // W1t
constexpr int S3 = S2 + 12 * 512;           // vcomb
constexpr int S4 = S3 + 256;                // partials zero
__global__ __launch_bounds__(256) void prep_kernel(
    const float* __restrict__ feats, const float* __restrict__ W1,
    const float* __restrict__ W2, const float* __restrict__ al2,
    const float* __restrict__ ar2, const float* __restrict__ Wr,
    __hip_bfloat16* __restrict__ featsb, __hip_bfloat16* __restrict__ W1t,
    float* __restrict__ vcomb, float* __restrict__ partials,
    int* __restrict__ cnt) {
  int t = blockIdx.x * 256 + threadIdx.x;
  if (t < S0) {
    cnt[t] = 0;
  } else if (t < S1) {
    int u = t - S0;
    featsb[u] = __float2bfloat16(u < NN * 128 ? feats[u] : 0.f);
  } else if (t < S2) {
    int u = t - S1;                       // W1t[m][k], m=u>>7, k=u&127
    W1t[u] = __float2bfloat16(W1[(size_t)(u & 127) * 512 + (u >> 7)]);
  } else if (t < S3) {
    int u = t - S2;                       // vcomb[v][k]
    int v = u >> 9, k = u & 511;
    int h = (v < 4) ? v : (v < 8) ? v - 4 : v - 8;
    const float* vec = (v < 4) ? (al2 + h * 128)
                     : (v < 8) ? (ar2 + h * 128) : Wr;
    const float* wrow = W2 + (size_t)k * 512 + h * 128;
    float s = 0.f;
    for (int d = 0; d < 128; ++d) s += wrow[d] * vec[d];
    vcomb[u] = s;
  } else if (t < S4) {
    partials[t - S3] = 0.f;
  }
}

// ---------------- layer-1 bf16 MFMA GEMM + fused el/er epilogue, fp8 z ------
// Prologue: grid-stride padded-CSR fill (cnt zeroed by prep).
// z[Mpad][512] (fp8 e4m3) = A[Mpad][128] @ W1t[512][128]^T.  128x128 tile,
// 256 threads = 4 waves, each 64x64 via 4x4 mfma_16x16x32.  blockIdx.y = head
// (D=128 = tile width); el/er reduced from the fp32 accumulators (full
// precision — logits must not be quantized).  z fp8: payload only.
__global__ __launch_bounds__(256) void gemm1_kernel(
    const __hip_bfloat16* __restrict__ A,   // [Mpad][128] bf16
    const __hip_bfloat16* __restrict__ Bt,  // [512][128] bf16 (W1^T)
    unsigned char* __restrict__ C,          // [Mpad][512] fp8
    const float* __restrict__ al, const float* __restrict__ ar,
    float* __restrict__ el, float* __restrict__ er,
    const int* __restrict__ src, const int* __restrict__ dst,
    int* __restrict__ cnt, int* __restrict__ src_perm) {
  constexpr int K = 128;
  __shared__ short As[128 * 32];
  __shared__ short Bs[128 * 32];
  __shared__ float elbuf[4][128];
  __shared__ float erbuf[4][128];
  int t = threadIdx.x;

  // ---- CSR fill prologue (completes before aggregate by stream order) ----
  {
    int nth = gridDim.x * gridDim.y * 256;
    int gid = (blockIdx.y * gridDim.x + blockIdx.x) * 256 + t;
    for (int e = gid; e < NE; e += nth) {
      int d = dst[e];
      int p = atomicAdd(&cnt[d], 1);
      if (p < SLOTS) src_perm[d * SLOTS + p] = src[e];
    }
  }

  int lane = t & 63;
  int wave = t >> 6;
  int rowBase = blockIdx.x * 128;
  int head = blockIdx.y;
  int colBase = head * 128;
  int woffr = (wave & 1) * 64;
  int woffc = (wave >> 1) * 64;
  int mrow = lane & 15, quad = lane >> 4;

  f32x4 acc[4][4];
#pragma unroll
  for (int i = 0; i < 4; ++i)
#pragma unroll
    for (int j = 0; j < 4; ++j) acc[i][j] = (f32x4){0.f, 0.f, 0.f, 0.f};

  for (int k0 = 0; k0 < K; k0 += 32) {
#pragma unroll
    for (int p = 0; p < 2; ++p) {
      int f = p * 256 + wave * 64 + lane;
      int r = f >> 2, kc = f & 3;
      gload16(A + (size_t)(rowBase + r) * K + k0 + kc * 8,
              As + p * 2048 + wave * 512);
      gload16(Bt + (size_t)(colBase + r) * K + k0 + kc * 8,
              Bs + p * 2048 + wave * 512);
    }
    __syncthreads();
    short8 af[4], bfr[4];
#pragma unroll
    for (int i = 0; i < 4; ++i)
      af[i] = *(const short8*)&As[(woffr + i * 16 + mrow) * 32 + quad * 8];
#pragma unroll
    for (int j = 0; j < 4; ++j)
      bfr[j] = *(const short8*)&Bs[(woffc + j * 16 + mrow) * 32 + quad * 8];
#pragma unroll
    for (int i = 0; i < 4; ++i)
#pragma unroll
      for (int j = 0; j < 4; ++j)
        acc[i][j] = __builtin_amdgcn_mfma_f32_16x16x32_bf16(af[i], bfr[j], acc[i][j], 0, 0, 0);
    __syncthreads();
  }

  // z store (fp8). C/D layout: col = lane&15, row = quad*4 + reg (m89/m91)
#pragma unroll
  for (int i = 0; i < 4; ++i) {
#pragma unroll
    for (int j = 0; j < 4; ++j) {
      int col = colBase + woffc + j * 16 + mrow;
#pragma unroll
      for (int r = 0; r < 4; ++r) {
        int row = rowBase + woffr + i * 16 + quad * 4 + r;
        C[(size_t)row * HD + col] = f32_to_fp8(acc[i][j][r]);
      }
    }
  }

  // fused el/er epilogue from fp32 accumulators
  float al_v[4], ar_v[4];
#pragma unroll
  for (int j = 0; j < 4; ++j) {
    int coll = woffc + j * 16 + mrow;
    al_v[j] = al[head * 128 + coll];
    ar_v[j] = ar[head * 128 + coll];
  }
#pragma unroll
  for (int i = 0; i < 4; ++i) {
#pragma unroll
    for (int r = 0; r < 4; ++r) {
      float pl = 0.f, pr = 0.f;
#pragma unroll
      for (int j = 0; j < 4; ++j) {
        float v = acc[i][j][r];
        pl += v * al_v[j];
        pr += v * ar_v[j];
      }
#pragma unroll
      for (int off = 1; off < 16; off <<= 1) {
        pl += __shfl_xor(pl, off);
        pr += __shfl_xor(pr, off);
      }
      if (mrow == 0) {
        int row128 = woffr + i * 16 + quad * 4 + r;
        elbuf[wave][row128] = pl;
        erbuf[wave][row128] = pr;
      }
    }
  }
  __syncthreads();
  if (t < 128) {
    int row = t;
    int w0 = (row < 64) ? 0 : 1;
    float ev = elbuf[w0][row] + elbuf[w0 + 2][row];
    float rv = erbuf[w0][row] + erbuf[w0 + 2][row];
    int gr = rowBase + row;
    if (gr < NN) {
      el[gr * 4 + head] = ev;
      er[gr * 4 + head] = rv;
    }
  }
}

// ---------------- fused attn + aggregation + layer-2 projection -------------
// One wave per node (the empirically-best structure: R7's wave-split and
// R14's head-split/XCD-pin both regressed).
// Phase 1 (lane = slot): alpha via exp(leaky_relu(el1[src]+er1[n])) (softmax
// shift-invariance -> segment_max skipped), butterfly denom; (alpha[h], src)
// PAIRS parked in LDS so phase 2 needs one ds_read_b64 + one global load per
// edge (src_perm is not re-read from global).
// Phase 2 (lane = dims, 4-deep unroll): h1 in fp32 registers
//   = ELU(sum_e alpha*z[src] + b1).
// Epilogue: h1 never stored — el2/er2/q are 12 dot products with the
// W2-folded vcomb vectors (GEMM2 eliminated algebraically; logits fp32).
struct __align__(8) APair { float a; int s; };
__global__ __launch_bounds__(256) void aggregate_kernel(
    const unsigned char* __restrict__ zf8,  // [MPAD][512] fp8
    const int* __restrict__ cnt,
    const int* __restrict__ src_perm,
    const float* __restrict__ el,           // layer-1 logits [NN][4]
    const float* __restrict__ er,
    const float* __restrict__ b1,           // [512]
    const float* __restrict__ vcomb,        // [12][512]
    float* __restrict__ el2,                // [NN][4]
    float* __restrict__ er2,                // [NN][4]
    float* __restrict__ q2) {               // [NN][4]
  __shared__ APair aslds[4][SLOTS][4];      // [wave][slot][head] (8 KB)
  int wv = __builtin_amdgcn_readfirstlane((int)(threadIdx.x >> 6));
  int n = blockIdx.x * 4 + wv;
  int lane = threadIdx.x & 63;
  int c = min(cnt[n], SLOTS);
  int base = n * SLOTS;

  // ---- phase 1: attention coefficients (lane = slot) ----
  {
    float4 er4 = *reinterpret_cast<const float4*>(&er[n * 4]);
    float a0 = 0.f, a1 = 0.f, a2 = 0.f, a3 = 0.f;
    int sv = 0;
    if (lane < c) {
      sv = src_perm[base + lane];
      float4 e4 = *reinterpret_cast<const float4*>(&el[sv * 4]);
      float x0 = e4.x + er4.x, x1 = e4.y + er4.y;
      float x2 = e4.z + er4.z, x3 = e4.w + er4.w;
      x0 = (x0 > 0.f) ? x0 : NEG_SLOPE * x0;
      x1 = (x1 > 0.f) ? x1 : NEG_SLOPE * x1;
      x2 = (x2 > 0.f) ? x2 : NEG_SLOPE * x2;
      x3 = (x3 > 0.f) ? x3 : NEG_SLOPE * x3;
      a0 = __expf(x0); a1 = __expf(x1); a2 = __expf(x2); a3 = __expf(x3);
    }
    float s0 = a0, s1 = a1, s2 = a2, s3 = a3;
#pragma unroll
    for (int off = 1; off < 64; off <<= 1) {
      s0 += __shfl_xor(s0, off);
      s1 += __shfl_xor(s1, off);
      s2 += __shfl_xor(s2, off);
      s3 += __shfl_xor(s3, off);
    }
    aslds[wv][lane][0] = {a0 / fmaxf(s0, 1e-9f), sv};
    aslds[wv][lane][1] = {a1 / fmaxf(s1, 1e-9f), sv};
    aslds[wv][lane][2] = {a2 / fmaxf(s2, 1e-9f), sv};
    aslds[wv][lane][3] = {a3 / fmaxf(s3, 1e-9f), sv};  // same-wave prod/cons
  }

  // ---- phase 2: payload aggregation (lane = dims), pairs from LDS ----
  int head = lane >> 4;
  float acc[8] = {};

#define EDGE_BODY(IDX)                                                         \
  {                                                                            \
    APair pr = aslds[wv][(IDX)][head];      /* one ds_read_b64: alpha + src */ \
    uint2 w = *reinterpret_cast<const uint2*>(zf8 + (size_t)pr.s * 512 + lane * 8); \
    f32x2 f0 = __builtin_amdgcn_cvt_pk_f32_fp8(w.x, false);                    \
    f32x2 f1 = __builtin_amdgcn_cvt_pk_f32_fp8(w.x, true);                     \
    f32x2 f2 = __builtin_amdgcn_cvt_pk_f32_fp8(w.y, false);                    \
    f32x2 f3 = __builtin_amdgcn_cvt_pk_f32_fp8(w.y, true);                     \
    acc[0] += pr.a * f0.x; acc[1] += pr.a * f0.y;                              \
    acc[2] += pr.a * f1.x; acc[3] += pr.a * f1.y;                              \
    acc[4] += pr.a * f2.x; acc[5] += pr.a * f2.y;                              \
    acc[6] += pr.a * f3.x; acc[7] += pr.a * f3.y;                              \
  }

  int i = 0;
  for (; i + 3 < c; i += 4) {
    EDGE_BODY(i)
    EDGE_BODY(i + 1)
    EDGE_BODY(i + 2)
    EDGE_BODY(i + 3)
  }
  for (; i < c; ++i) EDGE_BODY(i)
#undef EDGE_BODY

  float4 bA = *reinterpret_cast<const float4*>(&b1[lane * 8]);
  float4 bB = *reinterpret_cast<const float4*>(&b1[lane * 8 + 4]);
  float v[8];
  v[0] = acc[0] + bA.x; v[1] = acc[1] + bA.y;
  v[2] = acc[2] + bA.z; v[3] = acc[3] + bA.w;
  v[4] = acc[4] + bB.x; v[5] = acc[5] + bB.y;
  v[6] = acc[6] + bB.z; v[7] = acc[7] + bB.w;
#pragma unroll
  for (int j = 0; j < 8; ++j) v[j] = (v[j] > 0.f) ? v[j] : expm1f(v[j]);

  // ---- epilogue: el2/er2/q = h1 . vcomb (12 dots, butterfly reductions) ----
  float r[12];
#pragma unroll
  for (int vv = 0; vv < 12; ++vv) {
    const float* vb = vcomb + vv * 512 + lane * 8;
    float4 cA = *reinterpret_cast<const float4*>(vb);
    float4 cB = *reinterpret_cast<const float4*>(vb + 4);
    float p = v[0] * cA.x + v[1] * cA.y + v[2] * cA.z + v[3] * cA.w +
              v[4] * cB.x + v[5] * cB.y + v[6] * cB.z + v[7] * cB.w;
#pragma unroll
    for (int off = 1; off < 64; off <<= 1) p += __shfl_xor(p, off);
    r[vv] = p;
  }
  if (lane == 0) {
    *reinterpret_cast<float4*>(&el2[n * 4]) = make_float4(r[0], r[1], r[2], r[3]);
    *reinterpret_cast<float4*>(&er2[n * 4]) = make_float4(r[4], r[5], r[6], r[7]);
    *reinterpret_cast<float4*>(&q2[n * 4]) = make_float4(r[8], r[9], r[10], r[11]);
  }
}

// ---------------- layer-2 attention + readout dot ---------------------------
// One wave per dst node (lane = slot): alpha butterfly, dot with q[src] (16 B
// L2-resident gather), block partial -> 256-slot atomics.  NO device fence /
// done counter — that cost ~90 µs in R11; the tiny final kernel is cheaper.
__global__ __launch_bounds__(256) void attn_q_kernel(
    const int* __restrict__ src_perm,
    const int* __restrict__ cnt,
    const float* __restrict__ el,
    const float* __restrict__ er,
    const float* __restrict__ q,            // [NN][4]
    float* __restrict__ partials) {         // [256]
  __shared__ float blk[4];
  int wv = __builtin_amdgcn_readfirstlane((int)(threadIdx.x >> 6));
  int n = blockIdx.x * 4 + wv;
  int lane = threadIdx.x & 63;
  int c = min(cnt[n], SLOTS);
  float4 er4 = *reinterpret_cast<const float4*>(&er[n * 4]);
  float a0 = 0.f, a1 = 0.f, a2 = 0.f, a3 = 0.f;
  int s = 0;
  if (lane < c) {
    s = src_perm[n * SLOTS + lane];
    float4 e4 = *reinterpret_cast<const float4*>(&el[s * 4]);
    float x0 = e4.x + er4.x, x1 = e4.y + er4.y;
    float x2 = e4.z + er4.z, x3 = e4.w + er4.w;
    x0 = (x0 > 0.f) ? x0 : NEG_SLOPE * x0;
    x1 = (x1 > 0.f) ? x1 : NEG_SLOPE * x1;
    x2 = (x2 > 0.f) ? x2 : NEG_SLOPE * x2;
    x3 = (x3 > 0.f) ? x3 : NEG_SLOPE * x3;
    a0 = __expf(x0); a1 = __expf(x1); a2 = __expf(x2); a3 = __expf(x3);
  }
  float s0 = a0, s1 = a1, s2 = a2, s3 = a3;
#pragma unroll
  for (int off = 1; off < 64; off <<= 1) {
    s0 += __shfl_xor(s0, off);
    s1 += __shfl_xor(s1, off);
    s2 += __shfl_xor(s2, off);
    s3 += __shfl_xor(s3, off);
  }
  float p = 0.f;
  if (lane < c) {
    float4 q4 = *reinterpret_cast<const float4*>(&q[s * 4]);
    p = (a0 / fmaxf(s0, 1e-9f)) * q4.x + (a1 / fmaxf(s1, 1e-9f)) * q4.y +
        (a2 / fmaxf(s2, 1e-9f)) * q4.z + (a3 / fmaxf(s3, 1e-9f)) * q4.w;
  }
#pragma unroll
  for (int off = 32; off > 0; off >>= 1) p += __shfl_down(p, off);
  if (lane == 0) blk[wv] = p;
  __syncthreads();
  if (threadIdx.x == 0) {
    atomicAdd(&partials[blockIdx.x & 255], blk[0] + blk[1] + blk[2] + blk[3]);
  }
}

// ---------------- final: out = 0.25*(sum partials + NN*b2.Wr_rep) + NN*br ----
__global__ __launch_bounds__(512) void final_kernel(
    const float* __restrict__ partials, const float* __restrict__ b2,
    const float* __restrict__ Wr, const float* __restrict__ br,
    float* __restrict__ out) {
  __shared__ float tmp[512];
  int t = threadIdx.x;
  float sum = (t < 256) ? partials[t] : 0.f;
  sum += (float)NN * b2[t] * Wr[t & 127];
  tmp[t] = sum;
  __syncthreads();
  for (int off = 256; off > 0; off >>= 1) {
    if (t < off) tmp[t] += tmp[t + off];
    __syncthreads();
  }
  if (t == 0) out[0] = 0.25f * tmp[0] + (float)NN * br[0];
}

// ---------------- launch ----------------
extern "C" void kernel_launch(void* const* d_in, const int* in_sizes, int n_in,
                              void* d_out, int out_size, void* d_ws, size_t ws_size,
                              hipStream_t stream) {
  const float* feats = (const float*)d_in[0];
  const int* src = (const int*)d_in[1];
  const int* dst = (const int*)d_in[2];
  const float* W1 = (const float*)d_in[3];
  const float* al1 = (const float*)d_in[4];
  const float* ar1 = (const float*)d_in[5];
  const float* b1 = (const float*)d_in[6];
  const float* W2 = (const float*)d_in[7];
  const float* al2 = (const float*)d_in[8];
  const float* ar2 = (const float*)d_in[9];
  const float* b2 = (const float*)d_in[10];
  const float* Wr = (const float*)d_in[11];
  const float* br = (const float*)d_in[12];
  float* out = (float*)d_out;

  // workspace layout (~22 MB); all section sizes multiples of 16 B
  __hip_bfloat16* featsb = (__hip_bfloat16*)d_ws;               // MPAD*128 bf16
  unsigned char* zf8 = (unsigned char*)(featsb + (size_t)MPAD * 128); // MPAD*512 fp8
  __hip_bfloat16* W1t = (__hip_bfloat16*)(zf8 + (size_t)MPAD * HD);   // 512*128 bf16
  float* vcomb = (float*)(W1t + 512 * 128);                     // 12*512 f32
  float* el1 = vcomb + 12 * 512;                                // NN*4
  float* er1 = el1 + (size_t)NN * NHEAD;                        // NN*4
  float* el2 = er1 + (size_t)NN * NHEAD;                        // NN*4
  float* er2 = el2 + (size_t)NN * NHEAD;                        // NN*4
  float* q2 = er2 + (size_t)NN * NHEAD;                         // NN*4
  float* partials = q2 + (size_t)NN * NHEAD;                    // 256
  int* cnt = (int*)(partials + 256 + 4);                        // NN
  int* src_perm = cnt + NN;                                     // NN*SLOTS

  // prep: cnt zero + feats->bf16 + W1^T + vcomb + partials zero (1 dispatch)
  prep_kernel<<<(S4 + 255) / 256, 256, 0, stream>>>(
      feats, W1, W2, al2, ar2, Wr, featsb, W1t, vcomb, partials, cnt);

  dim3 gemm_grid(MPAD / 128, NHEAD);

  // gemm1: CSR-fill prologue + GEMM (fp8 z + el/er epilogue)
  gemm1_kernel<<<gemm_grid, 256, 0, stream>>>(featsb, W1t, zf8, al1, ar1,
                                              el1, er1, src, dst, cnt, src_perm);

  // fused: layer-1 attn+aggregate + layer-2 projections (GEMM2 folded)
  aggregate_kernel<<<NN / 4, 256, 0, stream>>>(zf8, cnt, src_perm, el1, er1, b1,
                                               vcomb, el2, er2, q2);

  // layer-2 attention + readout dot, then tiny final reduce
  attn_q_kernel<<<NN / 4, 256, 0, stream>>>(src_perm, cnt, el2, er2, q2, partials);
  final_kernel<<<1, 512, 0, stream>>>(partials, b2, Wr, br, out);
}

// Round 16
// 172.722 us; speedup vs baseline: 1.4243x; 1.0117x over previous
//
#include <hip/hip_runtime.h>
#include <hip/hip_bf16.h>
#include <cstddef>

// Problem constants (match reference)
constexpr int NN = 20000;   // nodes
constexpr int NE = 320000;  // edges
constexpr int NHEAD = 4;
constexpr int ND = 128;     // per-head dim
constexpr int HD = 512;     // H*D
constexpr int MPAD = 20096; // 157*128 padded rows for GEMM tiles
constexpr int SLOTS = 64;   // padded-CSR slots per node (Poisson(16): P(>64)~1e-20)
constexpr float NEG_SLOPE = 0.2f;

using short8 = __attribute__((ext_vector_type(8))) short;
using f32x4 = __attribute__((ext_vector_type(4))) float;
using f32x2 = __attribute__((ext_vector_type(2))) float;

// async global->LDS, 16B per lane, LDS dest = wave-uniform base + lane*16
__device__ inline void gload16(const void* g, void* l) {
  __builtin_amdgcn_global_load_lds(
      (const __attribute__((address_space(1))) void*)g,
      (__attribute__((address_space(3))) void*)l, 16, 0, 0);
}

// fp8 e4m3 (OCP on gfx950) encode one float -> byte
__device__ inline unsigned char f32_to_fp8(float v) {
  int pk = __builtin_amdgcn_cvt_pk_fp8_f32(v, v, 0, false);
  return (unsigned char)(pk & 0xff);
}

// fast 1/x (v_rcp_f32, ~1 ulp) — replaces full-precision divide (rcp+Newton)
__device__ inline float fastrcp(float x) { return __builtin_amdgcn_rcpf(x); }

// fast ELU negative branch: expm1f is a ~30-inst libm polynomial; expf-1 is
// 3 inst (mul+v_exp+sub).  Cancellation only matters for |x|<<1 where the
// absolute error is ~1e-7 — invisible at our 1.085 absmax budget.
__device__ inline float fast_elu(float x) {
  return (x > 0.f) ? x : (__expf(x) - 1.0f);
}

// ---------------- fused prep --------------------------------------------------
// Segments: [cnt zero][feats->bf16 pad][W1^T bf16][vcomb][partials zero]
// vcomb[v][k], v = 0..11: v<4 -> vl[h=v], v<8 -> vr[h=v-4], else vq[h=v-8]:
//   vl[h,k] = sum_d W2[k, h*128+d] * al2[h,d]   (el2 = h1 . vl, fp32 — the
//   attention logits keep full precision; fp8 logits failed in R10)
constexpr int S0 = NN;                      // cnt zero
constexpr int S1 = S0 + MPAD * 128;         // featsb
constexpr int S2 = S1 + 512 * 128;          // W1t
constexpr int S3 = S2 + 12 * 512;           // vcomb
constexpr int S4 = S3 + 256;                // partials zero
__global__ __launch_bounds__(256) void prep_kernel(
    const float* __restrict__ feats, const float* __restrict__ W1,
    const float* __restrict__ W2, const float* __restrict__ al2,
    const float* __restrict__ ar2, const float* __restrict__ Wr,
    __hip_bfloat16* __restrict__ featsb, __hip_bfloat16* __restrict__ W1t,
    float* __restrict__ vcomb, float* __restrict__ partials,
    int* __restrict__ cnt) {
  int t = blockIdx.x * 256 + threadIdx.x;
  if (t < S0) {
    cnt[t] = 0;
  } else if (t < S1) {
    int u = t - S0;
    featsb[u] = __float2bfloat16(u < NN * 128 ? feats[u] : 0.f);
  } else if (t < S2) {
    int u = t - S1;                       // W1t[m][k], m=u>>7, k=u&127
    W1t[u] = __float2bfloat16(W1[(size_t)(u & 127) * 512 + (u >> 7)]);
  } else if (t < S3) {
    int u = t - S2;                       // vcomb[v][k]
    int v = u >> 9, k = u & 511;
    int h = (v < 4) ? v : (v < 8) ? v - 4 : v - 8;
    const float* vec = (v < 4) ? (al2 + h * 128)
                     : (v < 8) ? (ar2 + h * 128) : Wr;
    const float* wrow = W2 + (size_t)k * 512 + h * 128;
    float s = 0.f;
    for (int d = 0; d < 128; ++d) s += wrow[d] * vec[d];
    vcomb[u] = s;
  } else if (t < S4) {
    partials[t - S3] = 0.f;
  }
}

// ---------------- layer-1 bf16 MFMA GEMM + fused el/er epilogue, fp8 z ------
// Prologue: grid-stride padded-CSR fill (cnt zeroed by prep).
// z[Mpad][512] (fp8 e4m3) = A[Mpad][128] @ W1t[512][128]^T.  128x128 tile,
// 256 threads = 4 waves, each 64x64 via 4x4 mfma_16x16x32.  blockIdx.y = head
// (D=128 = tile width); el/er reduced from the fp32 accumulators (full
// precision — logits must not be quantized).  z fp8: payload only.
__global__ __launch_bounds__(256) void gemm1_kernel(
    const __hip_bfloat16* __restrict__ A,   // [Mpad][128] bf16
    const __hip_bfloat16* __restrict__ Bt,  // [512][128] bf16 (W1^T)
    unsigned char* __restrict__ C,          // [Mpad][512] fp8
    const float* __restrict__ al, const float* __restrict__ ar,
    float* __restrict__ el, float* __restrict__ er,
    const int* __restrict__ src, const int* __restrict__ dst,
    int* __restrict__ cnt, int* __restrict__ src_perm) {
  constexpr int K = 128;
  __shared__ short As[128 * 32];
  __shared__ short Bs[128 * 32];
  __shared__ float elbuf[4][128];
  __shared__ float erbuf[4][128];
  int t = threadIdx.x;

  // ---- CSR fill prologue (completes before aggregate by stream order) ----
  {
    int nth = gridDim.x * gridDim.y * 256;
    int gid = (blockIdx.y * gridDim.x + blockIdx.x) * 256 + t;
    for (int e = gid; e < NE; e += nth) {
      int d = dst[e];
      int p = atomicAdd(&cnt[d], 1);
      if (p < SLOTS) src_perm[d * SLOTS + p] = src[e];
    }
  }

  int lane = t & 63;
  int wave = t >> 6;
  int rowBase = blockIdx.x * 128;
  int head = blockIdx.y;
  int colBase = head * 128;
  int woffr = (wave & 1) * 64;
  int woffc = (wave >> 1) * 64;
  int mrow = lane & 15, quad = lane >> 4;

  f32x4 acc[4][4];
#pragma unroll
  for (int i = 0; i < 4; ++i)
#pragma unroll
    for (int j = 0; j < 4; ++j) acc[i][j] = (f32x4){0.f, 0.f, 0.f, 0.f};

  for (int k0 = 0; k0 < K; k0 += 32) {
#pragma unroll
    for (int p = 0; p < 2; ++p) {
      int f = p * 256 + wave * 64 + lane;
      int r = f >> 2, kc = f & 3;
      gload16(A + (size_t)(rowBase + r) * K + k0 + kc * 8,
              As + p * 2048 + wave * 512);
      gload16(Bt + (size_t)(colBase + r) * K + k0 + kc * 8,
              Bs + p * 2048 + wave * 512);
    }
    __syncthreads();
    short8 af[4], bfr[4];
#pragma unroll
    for (int i = 0; i < 4; ++i)
      af[i] = *(const short8*)&As[(woffr + i * 16 + mrow) * 32 + quad * 8];
#pragma unroll
    for (int j = 0; j < 4; ++j)
      bfr[j] = *(const short8*)&Bs[(woffc + j * 16 + mrow) * 32 + quad * 8];
#pragma unroll
    for (int i = 0; i < 4; ++i)
#pragma unroll
      for (int j = 0; j < 4; ++j)
        acc[i][j] = __builtin_amdgcn_mfma_f32_16x16x32_bf16(af[i], bfr[j], acc[i][j], 0, 0, 0);
    __syncthreads();
  }

  // z store (fp8). C/D layout: col = lane&15, row = quad*4 + reg (m89/m91)
#pragma unroll
  for (int i = 0; i < 4; ++i) {
#pragma unroll
    for (int j = 0; j < 4; ++j) {
      int col = colBase + woffc + j * 16 + mrow;
#pragma unroll
      for (int r = 0; r < 4; ++r) {
        int row = rowBase + woffr + i * 16 + quad * 4 + r;
        C[(size_t)row * HD + col] = f32_to_fp8(acc[i][j][r]);
      }
    }
  }

  // fused el/er epilogue from fp32 accumulators
  float al_v[4], ar_v[4];
#pragma unroll
  for (int j = 0; j < 4; ++j) {
    int coll = woffc + j * 16 + mrow;
    al_v[j] = al[head * 128 + coll];
    ar_v[j] = ar[head * 128 + coll];
  }
#pragma unroll
  for (int i = 0; i < 4; ++i) {
#pragma unroll
    for (int r = 0; r < 4; ++r) {
      float pl = 0.f, pr = 0.f;
#pragma unroll
      for (int j = 0; j < 4; ++j) {
        float v = acc[i][j][r];
        pl += v * al_v[j];
        pr += v * ar_v[j];
      }
#pragma unroll
      for (int off = 1; off < 16; off <<= 1) {
        pl += __shfl_xor(pl, off);
        pr += __shfl_xor(pr, off);
      }
      if (mrow == 0) {
        int row128 = woffr + i * 16 + quad * 4 + r;
        elbuf[wave][row128] = pl;
        erbuf[wave][row128] = pr;
      }
    }
  }
  __syncthreads();
  if (t < 128) {
    int row = t;
    int w0 = (row < 64) ? 0 : 1;
    float ev = elbuf[w0][row] + elbuf[w0 + 2][row];
    float rv = erbuf[w0][row] + erbuf[w0 + 2][row];
    int gr = rowBase + row;
    if (gr < NN) {
      el[gr * 4 + head] = ev;
      er[gr * 4 + head] = rv;
    }
  }
}

// ---------------- fused attn + aggregation + layer-2 projection -------------
// One wave per node (the empirically-best structure: R7's wave-split and
// R14's head-split/XCD-pin both regressed).
// Phase 1 (lane = slot): alpha via exp(leaky_relu(el1[src]+er1[n])) (softmax
// shift-invariance -> segment_max skipped), butterfly denom; (alpha[h], src)
// PAIRS parked in LDS so phase 2 needs one ds_read_b64 + one global load per
// edge (src_perm is not re-read from global).
// Phase 2 (lane = dims, 4-deep unroll): h1 in fp32 registers
//   = fast_elu(sum_e alpha*z[src] + b1).
// Epilogue: h1 never stored — el2/er2/q are 12 dot products with the
// W2-folded vcomb vectors (GEMM2 eliminated algebraically; logits fp32).
struct __align__(8) APair { float a; int s; };
__global__ __launch_bounds__(256) void aggregate_kernel(
    const unsigned char* __restrict__ zf8,  // [MPAD][512] fp8
    const int* __restrict__ cnt,
    const int* __restrict__ src_perm,
    const float* __restrict__ el,           // layer-1 logits [NN][4]
    const float* __restrict__ er,
    const float* __restrict__ b1,           // [512]
    const float* __restrict__ vcomb,        // [12][512]
    float* __restrict__ el2,                // [NN][4]
    float* __restrict__ er2,                // [NN][4]
    float* __restrict__ q2) {               // [NN][4]
  __shared__ APair aslds[4][SLOTS][4];      // [wave][slot][head] (8 KB)
  int wv = __builtin_amdgcn_readfirstlane((int)(threadIdx.x >> 6));
  int n = blockIdx.x * 4 + wv;
  int lane = threadIdx.x & 63;
  int c = min(cnt[n], SLOTS);
  int base = n * SLOTS;

  // ---- phase 1: attention coefficients (lane = slot) ----
  {
    float4 er4 = *reinterpret_cast<const float4*>(&er[n * 4]);
    float a0 = 0.f, a1 = 0.f, a2 = 0.f, a3 = 0.f;
    int sv = 0;
    if (lane < c) {
      sv = src_perm[base + lane];
      float4 e4 = *reinterpret_cast<const float4*>(&el[sv * 4]);
      float x0 = e4.x + er4.x, x1 = e4.y + er4.y;
      float x2 = e4.z + er4.z, x3 = e4.w + er4.w;
      x0 = (x0 > 0.f) ? x0 : NEG_SLOPE * x0;
      x1 = (x1 > 0.f) ? x1 : NEG_SLOPE * x1;
      x2 = (x2 > 0.f) ? x2 : NEG_SLOPE * x2;
      x3 = (x3 > 0.f) ? x3 : NEG_SLOPE * x3;
      a0 = __expf(x0); a1 = __expf(x1); a2 = __expf(x2); a3 = __expf(x3);
    }
    float s0 = a0, s1 = a1, s2 = a2, s3 = a3;
#pragma unroll
    for (int off = 1; off < 64; off <<= 1) {
      s0 += __shfl_xor(s0, off);
      s1 += __shfl_xor(s1, off);
      s2 += __shfl_xor(s2, off);
      s3 += __shfl_xor(s3, off);
    }
    float i0 = fastrcp(fmaxf(s0, 1e-9f));
    float i1 = fastrcp(fmaxf(s1, 1e-9f));
    float i2 = fastrcp(fmaxf(s2, 1e-9f));
    float i3 = fastrcp(fmaxf(s3, 1e-9f));
    aslds[wv][lane][0] = {a0 * i0, sv};
    aslds[wv][lane][1] = {a1 * i1, sv};
    aslds[wv][lane][2] = {a2 * i2, sv};
    aslds[wv][lane][3] = {a3 * i3, sv};  // same-wave producer/consumer
  }

  // ---- phase 2: payload aggregation (lane = dims), pairs from LDS ----
  int head = lane >> 4;
  float acc[8] = {};

#define EDGE_BODY(IDX)                                                         \
  {                                                                            \
    APair pr = aslds[wv][(IDX)][head];      /* one ds_read_b64: alpha + src */ \
    uint2 w = *reinterpret_cast<const uint2*>(zf8 + (size_t)pr.s * 512 + lane * 8); \
    f32x2 f0 = __builtin_amdgcn_cvt_pk_f32_fp8(w.x, false);                    \
    f32x2 f1 = __builtin_amdgcn_cvt_pk_f32_fp8(w.x, true);                     \
    f32x2 f2 = __builtin_amdgcn_cvt_pk_f32_fp8(w.y, false);                    \
    f32x2 f3 = __builtin_amdgcn_cvt_pk_f32_fp8(w.y, true);                     \
    acc[0] += pr.a * f0.x; acc[1] += pr.a * f0.y;                              \
    acc[2] += pr.a * f1.x; acc[3] += pr.a * f1.y;                              \
    acc[4] += pr.a * f2.x; acc[5] += pr.a * f2.y;                              \
    acc[6] += pr.a * f3.x; acc[7] += pr.a * f3.y;                              \
  }

  int i = 0;
  for (; i + 3 < c; i += 4) {
    EDGE_BODY(i)
    EDGE_BODY(i + 1)
    EDGE_BODY(i + 2)
    EDGE_BODY(i + 3)
  }
  for (; i < c; ++i) EDGE_BODY(i)
#undef EDGE_BODY

  float4 bA = *reinterpret_cast<const float4*>(&b1[lane * 8]);
  float4 bB = *reinterpret_cast<const float4*>(&b1[lane * 8 + 4]);
  float v[8];
  v[0] = fast_elu(acc[0] + bA.x); v[1] = fast_elu(acc[1] + bA.y);
  v[2] = fast_elu(acc[2] + bA.z); v[3] = fast_elu(acc[3] + bA.w);
  v[4] = fast_elu(acc[4] + bB.x); v[5] = fast_elu(acc[5] + bB.y);
  v[6] = fast_elu(acc[6] + bB.z); v[7] = fast_elu(acc[7] + bB.w);

  // ---- epilogue: el2/er2/q = h1 . vcomb (12 dots, butterfly reductions) ----
  float r[12];
#pragma unroll
  for (int vv = 0; vv < 12; ++vv) {
    const float* vb = vcomb + vv * 512 + lane * 8;
    float4 cA = *reinterpret_cast<const float4*>(vb);
    float4 cB = *reinterpret_cast<const float4*>(vb + 4);
    float p = v[0] * cA.x + v[1] * cA.y + v[2] * cA.z + v[3] * cA.w +
              v[4] * cB.x + v[5] * cB.y + v[6] * cB.z + v[7] * cB.w;
#pragma unroll
    for (int off = 1; off < 64; off <<= 1) p += __shfl_xor(p, off);
    r[vv] = p;
  }
  if (lane == 0) {
    *reinterpret_cast<float4*>(&el2[n * 4]) = make_float4(r[0], r[1], r[2], r[3]);
    *reinterpret_cast<float4*>(&er2[n * 4]) = make_float4(r[4], r[5], r[6], r[7]);
    *reinterpret_cast<float4*>(&q2[n * 4]) = make_float4(r[8], r[9], r[10], r[11]);
  }
}

// ---------------- layer-2 attention + readout dot ---------------------------
// One wave per dst node (lane = slot): alpha butterfly, dot with q[src] (16 B
// L2-resident gather), block partial -> 256-slot atomics.  NO device fence /
// done counter — that cost ~90 µs in R11; the tiny final kernel is cheaper.
__global__ __launch_bounds__(256) void attn_q_kernel(
    const int* __restrict__ src_perm,
    const int* __restrict__ cnt,
    const float* __restrict__ el,
    const float* __restrict__ er,
    const float* __restrict__ q,            // [NN][4]
    float* __restrict__ partials) {         // [256]
  __shared__ float blk[4];
  int wv = __builtin_amdgcn_readfirstlane((int)(threadIdx.x >> 6));
  int n = blockIdx.x * 4 + wv;
  int lane = threadIdx.x & 63;
  int c = min(cnt[n], SLOTS);
  float4 er4 = *reinterpret_cast<const float4*>(&er[n * 4]);
  float a0 = 0.f, a1 = 0.f, a2 = 0.f, a3 = 0.f;
  int s = 0;
  if (lane < c) {
    s = src_perm[n * SLOTS + lane];
    float4 e4 = *reinterpret_cast<const float4*>(&el[s * 4]);
    float x0 = e4.x + er4.x, x1 = e4.y + er4.y;
    float x2 = e4.z + er4.z, x3 = e4.w + er4.w;
    x0 = (x0 > 0.f) ? x0 : NEG_SLOPE * x0;
    x1 = (x1 > 0.f) ? x1 : NEG_SLOPE * x1;
    x2 = (x2 > 0.f) ? x2 : NEG_SLOPE * x2;
    x3 = (x3 > 0.f) ? x3 : NEG_SLOPE * x3;
    a0 = __expf(x0); a1 = __expf(x1); a2 = __expf(x2); a3 = __expf(x3);
  }
  float s0 = a0, s1 = a1, s2 = a2, s3 = a3;
#pragma unroll
  for (int off = 1; off < 64; off <<= 1) {
    s0 += __shfl_xor(s0, off);
    s1 += __shfl_xor(s1, off);
    s2 += __shfl_xor(s2, off);
    s3 += __shfl_xor(s3, off);
  }
  float p = 0.f;
  if (lane < c) {
    float4 q4 = *reinterpret_cast<const float4*>(&q[s * 4]);
    p = (a0 * fastrcp(fmaxf(s0, 1e-9f))) * q4.x +
        (a1 * fastrcp(fmaxf(s1, 1e-9f))) * q4.y +
        (a2 * fastrcp(fmaxf(s2, 1e-9f))) * q4.z +
        (a3 * fastrcp(fmaxf(s3, 1e-9f))) * q4.w;
  }
#pragma unroll
  for (int off = 32; off > 0; off >>= 1) p += __shfl_down(p, off);
  if (lane == 0) blk[wv] = p;
  __syncthreads();
  if (threadIdx.x == 0) {
    atomicAdd(&partials[blockIdx.x & 255], blk[0] + blk[1] + blk[2] + blk[3]);
  }
}

// ---------------- final: out = 0.25*(sum partials + NN*b2.Wr_rep) + NN*br ----
__global__ __launch_bounds__(512) void final_kernel(
    const float* __restrict__ partials, const float* __restrict__ b2,
    const float* __restrict__ Wr, const float* __restrict__ br,
    float* __restrict__ out) {
  __shared__ float tmp[512];
  int t = threadIdx.x;
  float sum = (t < 256) ? partials[t] : 0.f;
  sum += (float)NN * b2[t] * Wr[t & 127];
  tmp[t] = sum;
  __syncthreads();
  for (int off = 256; off > 0; off >>= 1) {
    if (t < off) tmp[t] += tmp[t + off];
    __syncthreads();
  }
  if (t == 0) out[0] = 0.25f * tmp[0] + (float)NN * br[0];
}

// ---------------- launch ----------------
extern "C" void kernel_launch(void* const* d_in, const int* in_sizes, int n_in,
                              void* d_out, int out_size, void* d_ws, size_t ws_size,
                              hipStream_t stream) {
  const float* feats = (const float*)d_in[0];
  const int* src = (const int*)d_in[1];
  const int* dst = (const int*)d_in[2];
  const float* W1 = (const float*)d_in[3];
  const float* al1 = (const float*)d_in[4];
  const float* ar1 = (const float*)d_in[5];
  const float* b1 = (const float*)d_in[6];
  const float* W2 = (const float*)d_in[7];
  const float* al2 = (const float*)d_in[8];
  const float* ar2 = (const float*)d_in[9];
  const float* b2 = (const float*)d_in[10];
  const float* Wr = (const float*)d_in[11];
  const float* br = (const float*)d_in[12];
  float* out = (float*)d_out;

  // workspace layout (~22 MB); all section sizes multiples of 16 B
  __hip_bfloat16* featsb = (__hip_bfloat16*)d_ws;               // MPAD*128 bf16
  unsigned char* zf8 = (unsigned char*)(featsb + (size_t)MPAD * 128); // MPAD*512 fp8
  __hip_bfloat16* W1t = (__hip_bfloat16*)(zf8 + (size_t)MPAD * HD);   // 512*128 bf16
  float* vcomb = (float*)(W1t + 512 * 128);                     // 12*512 f32
  float* el1 = vcomb + 12 * 512;                                // NN*4
  float* er1 = el1 + (size_t)NN * NHEAD;                        // NN*4
  float* el2 = er1 + (size_t)NN * NHEAD;                        // NN*4
  float* er2 = el2 + (size_t)NN * NHEAD;                        // NN*4
  float* q2 = er2 + (size_t)NN * NHEAD;                         // NN*4
  float* partials = q2 + (size_t)NN * NHEAD;                    // 256
  int* cnt = (int*)(partials + 256 + 4);                        // NN
  int* src_perm = cnt + NN;                                     // NN*SLOTS

  // prep: cnt zero + feats->bf16 + W1^T + vcomb + partials zero (1 dispatch)
  prep_kernel<<<(S4 + 255) / 256, 256, 0, stream>>>(
      feats, W1, W2, al2, ar2, Wr, featsb, W1t, vcomb, partials, cnt);

  dim3 gemm_grid(MPAD / 128, NHEAD);

  // gemm1: CSR-fill prologue + GEMM (fp8 z + el/er epilogue)
  gemm1_kernel<<<gemm_grid, 256, 0, stream>>>(featsb, W1t, zf8, al1, ar1,
                                              el1, er1, src, dst, cnt, src_perm);

  // fused: layer-1 attn+aggregate + layer-2 projections (GEMM2 folded)
  aggregate_kernel<<<NN / 4, 256, 0, stream>>>(zf8, cnt, src_perm, el1, er1, b1,
                                               vcomb, el2, er2, q2);

  // layer-2 attention + readout dot, then tiny final reduce
  attn_q_kernel<<<NN / 4, 256, 0, stream>>>(src_perm, cnt, el2, er2, q2, partials);
  final_kernel<<<1, 512, 0, stream>>>(partials, b2, Wr, br, out);
}

// Round 17
// 170.609 us; speedup vs baseline: 1.4419x; 1.0124x over previous
//
#include <hip/hip_runtime.h>
#include <hip/hip_bf16.h>
#include <cstddef>

// Problem constants (match reference)
constexpr int NN = 20000;   // nodes
constexpr int NE = 320000;  // edges
constexpr int NHEAD = 4;
constexpr int ND = 128;     // per-head dim
constexpr int HD = 512;     // H*D
constexpr int MPAD = 20096; // 157*128 padded rows for GEMM tiles
constexpr int SLOTS = 64;   // padded-CSR slots per node (Poisson(16): P(>64)~1e-20)
constexpr float NEG_SLOPE = 0.2f;

using short8 = __attribute__((ext_vector_type(8))) short;
using f32x4 = __attribute__((ext_vector_type(4))) float;
using f32x2 = __attribute__((ext_vector_type(2))) float;

// async global->LDS, 16B per lane, LDS dest = wave-uniform base + lane*16
__device__ inline void gload16(const void* g, void* l) {
  __builtin_amdgcn_global_load_lds(
      (const __attribute__((address_space(1))) void*)g,
      (__attribute__((address_space(3))) void*)l, 16, 0, 0);
}

// fp8 e4m3 (OCP on gfx950) encode one float -> byte
__device__ inline unsigned char f32_to_fp8(float v) {
  int pk = __builtin_amdgcn_cvt_pk_fp8_f32(v, v, 0, false);
  return (unsigned char)(pk & 0xff);
}

// fast 1/x (v_rcp_f32, ~1 ulp) — replaces full-precision divide (rcp+Newton)
__device__ inline float fastrcp(float x) { return __builtin_amdgcn_rcpf(x); }

// fast ELU negative branch: expm1f is a ~30-inst libm polynomial; expf-1 is
// 3 inst.  Cancellation only matters for |x|<<1 where the absolute error is
// ~1e-7 — invisible at our 1.085 absmax budget.
__device__ inline float fast_elu(float x) {
  return (x > 0.f) ? x : (__expf(x) - 1.0f);
}

// ---------------- fused prep --------------------------------------------------
// Segments: [cnt zero][feats->bf16 pad, FLOAT4-vectorized][W1^T bf16][vcomb]
//           [partials zero]
// vcomb[v][k], v = 0..11: v<4 -> vl[h=v], v<8 -> vr[h=v-4], else vq[h=v-8]:
//   vl[h,k] = sum_d W2[k, h*128+d] * al2[h,d]   (el2 = h1 . vl, fp32 — the
//   attention logits keep full precision; fp8 logits failed in R10)
constexpr int S0 = NN;                      // cnt zero
constexpr int S1 = S0 + MPAD * 128 / 4;     // featsb (4 elems per item)
constexpr int S2 = S1 + 512 * 128;          // W1t
constexpr int S3 = S2 + 12 * 512;           // vcomb
constexpr int S4 = S3 + 256;                // partials zero
__global__ __launch_bounds__(256) void prep_kernel(
    const float* __restrict__ feats, const float* __restrict__ W1,
    const float* __restrict__ W2, const float* __restrict__ al2,
    const float* __restrict__ ar2, const float* __restrict__ Wr,
    __hip_bfloat16* __restrict__ featsb, __hip_bfloat16* __restrict__ W1t,
    float* __restrict__ vcomb, float* __restrict__ partials,
    int* __restrict__ cnt) {
  int t = blockIdx.x * 256 + threadIdx.x;
  if (t < S0) {
    cnt[t] = 0;
  } else if (t < S1) {
    int u = (t - S0) * 4;                 // NN*128 = 2560000 is 4-aligned
    float4 f = (u < NN * 128) ? *reinterpret_cast<const float4*>(&feats[u])
                              : make_float4(0.f, 0.f, 0.f, 0.f);
    __hip_bfloat162 o0 = __float22bfloat162_rn(make_float2(f.x, f.y));
    __hip_bfloat162 o1 = __float22bfloat162_rn(make_float2(f.z, f.w));
    uint2 pk;
    pk.x = *reinterpret_cast<unsigned int*>(&o0);
    pk.y = *reinterpret_cast<unsigned int*>(&o1);
    *reinterpret_cast<uint2*>(&featsb[u]) = pk;
  } else if (t < S2) {
    int u = t - S1;                       // W1t[m][k], m=u>>7, k=u&127
    W1t[u] = __float2bfloat16(W1[(size_t)(u & 127) * 512 + (u >> 7)]);
  } else if (t < S3) {
    int u = t - S2;                       // vcomb[v][k]
    int v = u >> 9, k = u & 511;
    int h = (v < 4) ? v : (v < 8) ? v - 4 : v - 8;
    const float* vec = (v < 4) ? (al2 + h * 128)
                     : (v < 8) ? (ar2 + h * 128) : Wr;
    const float* wrow = W2 + (size_t)k * 512 + h * 128;
    float s = 0.f;
    for (int d = 0; d < 128; ++d) s += wrow[d] * vec[d];
    vcomb[u] = s;
  } else if (t < S4) {
    partials[t - S3] = 0.f;
  }
}

// ---------------- layer-1 bf16 MFMA GEMM + fused el/er epilogue, fp8 z ------
// Prologue: grid-stride padded-CSR fill (cnt zeroed by prep).
// z[Mpad][512] (fp8 e4m3) = A[Mpad][128] @ W1t[512][128]^T.  128x128 tile,
// 256 threads = 4 waves, each 64x64 via 4x4 mfma_16x16x32.  blockIdx.y = head
// (D=128 = tile width); el/er reduced from the fp32 accumulators (full
// precision — logits must not be quantized).  z fp8: payload only.
__global__ __launch_bounds__(256) void gemm1_kernel(
    const __hip_bfloat16* __restrict__ A,   // [Mpad][128] bf16
    const __hip_bfloat16* __restrict__ Bt,  // [512][128] bf16 (W1^T)
    unsigned char* __restrict__ C,          // [Mpad][512] fp8
    const float* __restrict__ al, const float* __restrict__ ar,
    float* __restrict__ el, float* __restrict__ er,
    const int* __restrict__ src, const int* __restrict__ dst,
    int* __restrict__ cnt, int* __restrict__ src_perm) {
  constexpr int K = 128;
  __shared__ short As[128 * 32];
  __shared__ short Bs[128 * 32];
  __shared__ float elbuf[4][128];
  __shared__ float erbuf[4][128];
  int t = threadIdx.x;

  // ---- CSR fill prologue (completes before aggregate by stream order) ----
  {
    int nth = gridDim.x * gridDim.y * 256;
    int gid = (blockIdx.y * gridDim.x + blockIdx.x) * 256 + t;
    for (int e = gid; e < NE; e += nth) {
      int d = dst[e];
      int p = atomicAdd(&cnt[d], 1);
      if (p < SLOTS) src_perm[d * SLOTS + p] = src[e];
    }
  }

  int lane = t & 63;
  int wave = t >> 6;
  int rowBase = blockIdx.x * 128;
  int head = blockIdx.y;
  int colBase = head * 128;
  int woffr = (wave & 1) * 64;
  int woffc = (wave >> 1) * 64;
  int mrow = lane & 15, quad = lane >> 4;

  f32x4 acc[4][4];
#pragma unroll
  for (int i = 0; i < 4; ++i)
#pragma unroll
    for (int j = 0; j < 4; ++j) acc[i][j] = (f32x4){0.f, 0.f, 0.f, 0.f};

  for (int k0 = 0; k0 < K; k0 += 32) {
#pragma unroll
    for (int p = 0; p < 2; ++p) {
      int f = p * 256 + wave * 64 + lane;
      int r = f >> 2, kc = f & 3;
      gload16(A + (size_t)(rowBase + r) * K + k0 + kc * 8,
              As + p * 2048 + wave * 512);
      gload16(Bt + (size_t)(colBase + r) * K + k0 + kc * 8,
              Bs + p * 2048 + wave * 512);
    }
    __syncthreads();
    short8 af[4], bfr[4];
#pragma unroll
    for (int i = 0; i < 4; ++i)
      af[i] = *(const short8*)&As[(woffr + i * 16 + mrow) * 32 + quad * 8];
#pragma unroll
    for (int j = 0; j < 4; ++j)
      bfr[j] = *(const short8*)&Bs[(woffc + j * 16 + mrow) * 32 + quad * 8];
#pragma unroll
    for (int i = 0; i < 4; ++i)
#pragma unroll
      for (int j = 0; j < 4; ++j)
        acc[i][j] = __builtin_amdgcn_mfma_f32_16x16x32_bf16(af[i], bfr[j], acc[i][j], 0, 0, 0);
    __syncthreads();
  }

  // z store (fp8). C/D layout: col = lane&15, row = quad*4 + reg (m89/m91)
#pragma unroll
  for (int i = 0; i < 4; ++i) {
#pragma unroll
    for (int j = 0; j < 4; ++j) {
      int col = colBase + woffc + j * 16 + mrow;
#pragma unroll
      for (int r = 0; r < 4; ++r) {
        int row = rowBase + woffr + i * 16 + quad * 4 + r;
        C[(size_t)row * HD + col] = f32_to_fp8(acc[i][j][r]);
      }
    }
  }

  // fused el/er epilogue from fp32 accumulators
  float al_v[4], ar_v[4];
#pragma unroll
  for (int j = 0; j < 4; ++j) {
    int coll = woffc + j * 16 + mrow;
    al_v[j] = al[head * 128 + coll];
    ar_v[j] = ar[head * 128 + coll];
  }
#pragma unroll
  for (int i = 0; i < 4; ++i) {
#pragma unroll
    for (int r = 0; r < 4; ++r) {
      float pl = 0.f, pr = 0.f;
#pragma unroll
      for (int j = 0; j < 4; ++j) {
        float v = acc[i][j][r];
        pl += v * al_v[j];
        pr += v * ar_v[j];
      }
#pragma unroll
      for (int off = 1; off < 16; off <<= 1) {
        pl += __shfl_xor(pl, off);
        pr += __shfl_xor(pr, off);
      }
      if (mrow == 0) {
        int row128 = woffr + i * 16 + quad * 4 + r;
        elbuf[wave][row128] = pl;
        erbuf[wave][row128] = pr;
      }
    }
  }
  __syncthreads();
  if (t < 128) {
    int row = t;
    int w0 = (row < 64) ? 0 : 1;
    float ev = elbuf[w0][row] + elbuf[w0 + 2][row];
    float rv = erbuf[w0][row] + erbuf[w0 + 2][row];
    int gr = rowBase + row;
    if (gr < NN) {
      el[gr * 4 + head] = ev;
      er[gr * 4 + head] = rv;
    }
  }
}

// ---------------- fused attn + aggregation + layer-2 projection -------------
// One wave per node (the empirically-best structure: R7's wave-split and
// R14's head-split/XCD-pin both regressed).
// Phase 1 (lane = slot): alpha via exp(leaky_relu(el1[src]+er1[n])) (softmax
// shift-invariance -> segment_max skipped), butterfly denom; (alpha[h], src)
// PAIRS parked in LDS so phase 2 needs one ds_read_b64 + one global load per
// edge.
// Phase 2 (lane = dims, 4-deep unroll): h1 in fp32 registers
//   = fast_elu(sum_e alpha*z[src] + b1).
// Epilogue: h1 never stored — el2/er2/q are 12 dot products with the
// W2-folded vcomb vectors.  Reduction: 4-level intra-group butterfly + tiny
// same-wave LDS combine (saves ~40 wave-inst/node vs 12 full butterflies).
struct __align__(8) APair { float a; int s; };
__global__ __launch_bounds__(256) void aggregate_kernel(
    const unsigned char* __restrict__ zf8,  // [MPAD][512] fp8
    const int* __restrict__ cnt,
    const int* __restrict__ src_perm,
    const float* __restrict__ el,           // layer-1 logits [NN][4]
    const float* __restrict__ er,
    const float* __restrict__ b1,           // [512]
    const float* __restrict__ vcomb,        // [12][512]
    float* __restrict__ el2,                // [NN][4]
    float* __restrict__ er2,                // [NN][4]
    float* __restrict__ q2) {               // [NN][4]
  __shared__ APair aslds[4][SLOTS][4];      // [wave][slot][head] (8 KB)
  __shared__ float redbuf[4][12][4];        // [wave][dot][group] (768 B)
  int wv = __builtin_amdgcn_readfirstlane((int)(threadIdx.x >> 6));
  int n = blockIdx.x * 4 + wv;
  int lane = threadIdx.x & 63;
  int c = min(cnt[n], SLOTS);
  int base = n * SLOTS;

  // ---- phase 1: attention coefficients (lane = slot) ----
  {
    float4 er4 = *reinterpret_cast<const float4*>(&er[n * 4]);
    float a0 = 0.f, a1 = 0.f, a2 = 0.f, a3 = 0.f;
    int sv = 0;
    if (lane < c) {
      sv = src_perm[base + lane];
      float4 e4 = *reinterpret_cast<const float4*>(&el[sv * 4]);
      float x0 = e4.x + er4.x, x1 = e4.y + er4.y;
      float x2 = e4.z + er4.z, x3 = e4.w + er4.w;
      x0 = (x0 > 0.f) ? x0 : NEG_SLOPE * x0;
      x1 = (x1 > 0.f) ? x1 : NEG_SLOPE * x1;
      x2 = (x2 > 0.f) ? x2 : NEG_SLOPE * x2;
      x3 = (x3 > 0.f) ? x3 : NEG_SLOPE * x3;
      a0 = __expf(x0); a1 = __expf(x1); a2 = __expf(x2); a3 = __expf(x3);
    }
    float s0 = a0, s1 = a1, s2 = a2, s3 = a3;
#pragma unroll
    for (int off = 1; off < 64; off <<= 1) {
      s0 += __shfl_xor(s0, off);
      s1 += __shfl_xor(s1, off);
      s2 += __shfl_xor(s2, off);
      s3 += __shfl_xor(s3, off);
    }
    float i0 = fastrcp(fmaxf(s0, 1e-9f));
    float i1 = fastrcp(fmaxf(s1, 1e-9f));
    float i2 = fastrcp(fmaxf(s2, 1e-9f));
    float i3 = fastrcp(fmaxf(s3, 1e-9f));
    aslds[wv][lane][0] = {a0 * i0, sv};
    aslds[wv][lane][1] = {a1 * i1, sv};
    aslds[wv][lane][2] = {a2 * i2, sv};
    aslds[wv][lane][3] = {a3 * i3, sv};  // same-wave producer/consumer
  }

  // ---- phase 2: payload aggregation (lane = dims), pairs from LDS ----
  int head = lane >> 4;
  float acc[8] = {};

#define EDGE_BODY(IDX)                                                         \
  {                                                                            \
    APair pr = aslds[wv][(IDX)][head];      /* one ds_read_b64: alpha + src */ \
    uint2 w = *reinterpret_cast<const uint2*>(zf8 + (size_t)pr.s * 512 + lane * 8); \
    f32x2 f0 = __builtin_amdgcn_cvt_pk_f32_fp8(w.x, false);                    \
    f32x2 f1 = __builtin_amdgcn_cvt_pk_f32_fp8(w.x, true);                     \
    f32x2 f2 = __builtin_amdgcn_cvt_pk_f32_fp8(w.y, false);                    \
    f32x2 f3 = __builtin_amdgcn_cvt_pk_f32_fp8(w.y, true);                     \
    acc[0] += pr.a * f0.x; acc[1] += pr.a * f0.y;                              \
    acc[2] += pr.a * f1.x; acc[3] += pr.a * f1.y;                              \
    acc[4] += pr.a * f2.x; acc[5] += pr.a * f2.y;                              \
    acc[6] += pr.a * f3.x; acc[7] += pr.a * f3.y;                              \
  }

  int i = 0;
  for (; i + 3 < c; i += 4) {
    EDGE_BODY(i)
    EDGE_BODY(i + 1)
    EDGE_BODY(i + 2)
    EDGE_BODY(i + 3)
  }
  for (; i < c; ++i) EDGE_BODY(i)
#undef EDGE_BODY

  float4 bA = *reinterpret_cast<const float4*>(&b1[lane * 8]);
  float4 bB = *reinterpret_cast<const float4*>(&b1[lane * 8 + 4]);
  float v[8];
  v[0] = fast_elu(acc[0] + bA.x); v[1] = fast_elu(acc[1] + bA.y);
  v[2] = fast_elu(acc[2] + bA.z); v[3] = fast_elu(acc[3] + bA.w);
  v[4] = fast_elu(acc[4] + bB.x); v[5] = fast_elu(acc[5] + bB.y);
  v[6] = fast_elu(acc[6] + bB.z); v[7] = fast_elu(acc[7] + bB.w);

  // ---- epilogue: el2/er2/q = h1 . vcomb (12 dots) ----
  // 4-level butterfly within the 16-lane group, then lanes 0-11 combine the
  // 4 group partials from LDS (same-wave, no barrier).
  int li = lane & 15, g = lane >> 4;
#pragma unroll
  for (int vv = 0; vv < 12; ++vv) {
    const float* vb = vcomb + vv * 512 + lane * 8;
    float4 cA = *reinterpret_cast<const float4*>(vb);
    float4 cB = *reinterpret_cast<const float4*>(vb + 4);
    float p = v[0] * cA.x + v[1] * cA.y + v[2] * cA.z + v[3] * cA.w +
              v[4] * cB.x + v[5] * cB.y + v[6] * cB.z + v[7] * cB.w;
#pragma unroll
    for (int off = 1; off < 16; off <<= 1) p += __shfl_xor(p, off);
    if (li == 0) redbuf[wv][vv][g] = p;
  }
  if (lane < 12) {
    float s = redbuf[wv][lane][0] + redbuf[wv][lane][1] +
              redbuf[wv][lane][2] + redbuf[wv][lane][3];
    int h = lane & 3;
    float* dstp = (lane < 4) ? el2 : (lane < 8) ? er2 : q2;
    dstp[n * 4 + h] = s;
  }
}

// ---------------- layer-2 attention + readout dot ---------------------------
// One wave per dst node (lane = slot): alpha butterfly, dot with q[src] (16 B
// L2-resident gather), block partial -> 256-slot atomics.  NO device fence /
// done counter — that cost ~90 µs in R11; the tiny final kernel is cheaper.
__global__ __launch_bounds__(256) void attn_q_kernel(
    const int* __restrict__ src_perm,
    const int* __restrict__ cnt,
    const float* __restrict__ el,
    const float* __restrict__ er,
    const float* __restrict__ q,            // [NN][4]
    float* __restrict__ partials) {         // [256]
  __shared__ float blk[4];
  int wv = __builtin_amdgcn_readfirstlane((int)(threadIdx.x >> 6));
  int n = blockIdx.x * 4 + wv;
  int lane = threadIdx.x & 63;
  int c = min(cnt[n], SLOTS);
  float4 er4 = *reinterpret_cast<const float4*>(&er[n * 4]);
  float a0 = 0.f, a1 = 0.f, a2 = 0.f, a3 = 0.f;
  int s = 0;
  if (lane < c) {
    s = src_perm[n * SLOTS + lane];
    float4 e4 = *reinterpret_cast<const float4*>(&el[s * 4]);
    float x0 = e4.x + er4.x, x1 = e4.y + er4.y;
    float x2 = e4.z + er4.z, x3 = e4.w + er4.w;
    x0 = (x0 > 0.f) ? x0 : NEG_SLOPE * x0;
    x1 = (x1 > 0.f) ? x1 : NEG_SLOPE * x1;
    x2 = (x2 > 0.f) ? x2 : NEG_SLOPE * x2;
    x3 = (x3 > 0.f) ? x3 : NEG_SLOPE * x3;
    a0 = __expf(x0); a1 = __expf(x1); a2 = __expf(x2); a3 = __expf(x3);
  }
  float s0 = a0, s1 = a1, s2 = a2, s3 = a3;
#pragma unroll
  for (int off = 1; off < 64; off <<= 1) {
    s0 += __shfl_xor(s0, off);
    s1 += __shfl_xor(s1, off);
    s2 += __shfl_xor(s2, off);
    s3 += __shfl_xor(s3, off);
  }
  float p = 0.f;
  if (lane < c) {
    float4 q4 = *reinterpret_cast<const float4*>(&q[s * 4]);
    p = (a0 * fastrcp(fmaxf(s0, 1e-9f))) * q4.x +
        (a1 * fastrcp(fmaxf(s1, 1e-9f))) * q4.y +
        (a2 * fastrcp(fmaxf(s2, 1e-9f))) * q4.z +
        (a3 * fastrcp(fmaxf(s3, 1e-9f))) * q4.w;
  }
#pragma unroll
  for (int off = 32; off > 0; off >>= 1) p += __shfl_down(p, off);
  if (lane == 0) blk[wv] = p;
  __syncthreads();
  if (threadIdx.x == 0) {
    atomicAdd(&partials[blockIdx.x & 255], blk[0] + blk[1] + blk[2] + blk[3]);
  }
}

// ---------------- final: out = 0.25*(sum partials + NN*b2.Wr_rep) + NN*br ----
__global__ __launch_bounds__(512) void final_kernel(
    const float* __restrict__ partials, const float* __restrict__ b2,
    const float* __restrict__ Wr, const float* __restrict__ br,
    float* __restrict__ out) {
  __shared__ float tmp[512];
  int t = threadIdx.x;
  float sum = (t < 256) ? partials[t] : 0.f;
  sum += (float)NN * b2[t] * Wr[t & 127];
  tmp[t] = sum;
  __syncthreads();
  for (int off = 256; off > 0; off >>= 1) {
    if (t < off) tmp[t] += tmp[t + off];
    __syncthreads();
  }
  if (t == 0) out[0] = 0.25f * tmp[0] + (float)NN * br[0];
}

// ---------------- launch ----------------
extern "C" void kernel_launch(void* const* d_in, const int* in_sizes, int n_in,
                              void* d_out, int out_size, void* d_ws, size_t ws_size,
                              hipStream_t stream) {
  const float* feats = (const float*)d_in[0];
  const int* src = (const int*)d_in[1];
  const int* dst = (const int*)d_in[2];
  const float* W1 = (const float*)d_in[3];
  const float* al1 = (const float*)d_in[4];
  const float* ar1 = (const float*)d_in[5];
  const float* b1 = (const float*)d_in[6];
  const float* W2 = (const float*)d_in[7];
  const float* al2 = (const float*)d_in[8];
  const float* ar2 = (const float*)d_in[9];
  const float* b2 = (const float*)d_in[10];
  const float* Wr = (const float*)d_in[11];
  const float* br = (const float*)d_in[12];
  float* out = (float*)d_out;

  // workspace layout (~22 MB); all section sizes multiples of 16 B
  __hip_bfloat16* featsb = (__hip_bfloat16*)d_ws;               // MPAD*128 bf16
  unsigned char* zf8 = (unsigned char*)(featsb + (size_t)MPAD * 128); // MPAD*512 fp8
  __hip_bfloat16* W1t = (__hip_bfloat16*)(zf8 + (size_t)MPAD * HD);   // 512*128 bf16
  float* vcomb = (float*)(W1t + 512 * 128);                     // 12*512 f32
  float* el1 = vcomb + 12 * 512;                                // NN*4
  float* er1 = el1 + (size_t)NN * NHEAD;                        // NN*4
  float* el2 = er1 + (size_t)NN * NHEAD;                        // NN*4
  float* er2 = el2 + (size_t)NN * NHEAD;                        // NN*4
  float* q2 = er2 + (size_t)NN * NHEAD;                         // NN*4
  float* partials = q2 + (size_t)NN * NHEAD;                    // 256
  int* cnt = (int*)(partials + 256 + 4);                        // NN
  int* src_perm = cnt + NN;                                     // NN*SLOTS

  // prep: cnt zero + feats->bf16 + W1^T + vcomb + partials zero (1 dispatch)
  prep_kernel<<<(S4 + 255) / 256, 256, 0, stream>>>(
      feats, W1, W2, al2, ar2, Wr, featsb, W1t, vcomb, partials, cnt);

  dim3 gemm_grid(MPAD / 128, NHEAD);

  // gemm1: CSR-fill prologue + GEMM (fp8 z + el/er epilogue)
  gemm1_kernel<<<gemm_grid, 256, 0, stream>>>(featsb, W1t, zf8, al1, ar1,
                                              el1, er1, src, dst, cnt, src_perm);

  // fused: layer-1 attn+aggregate + layer-2 projections (GEMM2 folded)
  aggregate_kernel<<<NN / 4, 256, 0, stream>>>(zf8, cnt, src_perm, el1, er1, b1,
                                               vcomb, el2, er2, q2);

  // layer-2 attention + readout dot, then tiny final reduce
  attn_q_kernel<<<NN / 4, 256, 0, stream>>>(src_perm, cnt, el2, er2, q2, partials);
  final_kernel<<<1, 512, 0, stream>>>(partials, b2, Wr, br, out);
}